// Round 7
// baseline (221.585 us; speedup 1.0000x reference)
//
#include <hip/hip_runtime.h>

typedef __bf16 bf16x8 __attribute__((ext_vector_type(8)));
typedef __bf16 bf16x4 __attribute__((ext_vector_type(4)));
typedef float  f32x4  __attribute__((ext_vector_type(4)));

#define B_ 4
#define T_ 2048
#define H_ 8
#define D_ 64
#define E_ 512

// q scale: D^-0.5 * log2(e)  (softmax computed in exp2 domain)
#define QSCALE 0.18033688011112042f

// async global->LDS, 16B per lane. LDS dest is wave-uniform base + lane*16.
__device__ __forceinline__ void async_ld16(const __bf16* g, __bf16* lds) {
  __builtin_amdgcn_global_load_lds((const __attribute__((address_space(1))) void*)g,
                                   (__attribute__((address_space(3))) void*)lds,
                                   16, 0, 0);
}

// converts x, W_qkv (row-permuted to [which][h][d] order), W_0
__global__ void cvt_all(const float* __restrict__ x, const float* __restrict__ wq,
                        const float* __restrict__ w0, __bf16* __restrict__ xb,
                        __bf16* __restrict__ wqb, __bf16* __restrict__ w0b) {
  long i = (long)(blockIdx.x * 256 + threadIdx.x) * 8;
  const float* src; __bf16* dst; long roff, woff;
  if (i < 4194304L)      { src = x;  dst = xb;  roff = i; woff = i; }
  else if (i < 4980736L) {
    src = wq; dst = wqb; roff = i - 4194304L;
    // src row r = h*192 + d*3 + which  ->  dst row = which*512 + h*64 + d
    const int r = (int)(roff >> 9), c = (int)(roff & 511);
    const int h = r / 192, rem = r - h * 192;
    const int d = rem / 3, which = rem - d * 3;
    woff = (long)(which * 512 + h * 64 + d) * 512 + c;
  }
  else                   { src = w0; dst = w0b; roff = i - 4980736L; woff = roff; }
  float4 a = *(const float4*)(src + roff);
  float4 b = *(const float4*)(src + roff + 4);
  bf16x8 o;
  o[0] = (__bf16)a.x; o[1] = (__bf16)a.y; o[2] = (__bf16)a.z; o[3] = (__bf16)a.w;
  o[4] = (__bf16)b.x; o[5] = (__bf16)b.y; o[6] = (__bf16)b.z; o[7] = (__bf16)b.w;
  *(bf16x8*)(dst + woff) = o;
}

// C = A(MxK) * B(NxK)^T, K=512, TMx128 tile, 4 waves, 16x16x32 bf16 MFMA.
// BK=32, 3-slot LDS ring, prefetch depth 2, counted vmcnt (T3/T4).
// MODE 0 (TM=128): qkv epilogue (W pre-permuted -> which = n0>>9 block-uniform).
// MODE 1: plain fp32 store, row-major MxN.
template<int MODE, int N, int TM>
__global__ __launch_bounds__(256, TM == 128 ? 3 : 4)
void gemm_bt(const __bf16* __restrict__ A, const __bf16* __restrict__ Bm,
             __bf16* __restrict__ o0, __bf16* __restrict__ o1, __bf16* __restrict__ o2,
             float* __restrict__ of) {
  constexpr int K = 512;
  constexpr int MI = TM / 32;                 // acc tiles in m per wave
  constexpr int AL = TM / 64;                 // A slab-loads per wave per stage
  __shared__ __bf16 As[3][TM * 32];
  __shared__ __bf16 Bs[3][128 * 32];
  const int tid  = threadIdx.x;
  const int wave = tid >> 6, lane = tid & 63;
  const int l15 = lane & 15, l16 = lane >> 4;
  const int m0 = blockIdx.y * TM, n0 = blockIdx.x * 128;
  const int waveM = wave >> 1, waveN = wave & 1;
  // staging lane map: 16-row slab of 32 cols (64 B/row); lane -> (row, chunk)
  const int lr  = lane >> 2;
  const int lc8 = ((lane & 3) ^ ((lane >> 3) & 3)) * 8;

  f32x4 acc[MI][4] = {};

  const __bf16* ag = A  + (size_t)(m0 + wave * (AL * 16) + lr) * K + lc8;
  const __bf16* bg = Bm + (size_t)(n0 + wave * 32 + lr) * K + lc8;

  auto stage = [&](int buf, int k0) {
#pragma unroll
    for (int it = 0; it < AL; ++it)
      async_ld16(ag + (size_t)it * 16 * K + k0, &As[buf][(wave * AL + it) * 512]);
#pragma unroll
    for (int it = 0; it < 2; ++it)
      async_ld16(bg + (size_t)it * 16 * K + k0, &Bs[buf][(wave * 2 + it) * 512]);
  };

  stage(0, 0);
  stage(1, 32);
#pragma unroll
  for (int s = 0; s < 16; ++s) {
    if (s == 15) {
      asm volatile("s_waitcnt vmcnt(0)" ::: "memory");
    } else {
      if constexpr (AL == 2) asm volatile("s_waitcnt vmcnt(4)" ::: "memory");
      else                   asm volatile("s_waitcnt vmcnt(3)" ::: "memory");
    }
    __builtin_amdgcn_s_barrier();
    if (s < 14) stage((s + 2) % 3, (s + 2) * 32);
    const __bf16* Ac = As[s % 3];
    const __bf16* Bc = Bs[s % 3];
    bf16x8 af[MI], bfr[4];
#pragma unroll
    for (int i = 0; i < MI; ++i) {
      const int rA = waveM * (TM / 2) + i * 16 + l15;
      af[i] = *(const bf16x8*)&Ac[rA * 32 + ((l16 ^ ((rA >> 1) & 3)) * 8)];
    }
#pragma unroll
    for (int i = 0; i < 4; ++i) {
      const int rB = waveN * 64 + i * 16 + l15;
      bfr[i] = *(const bf16x8*)&Bc[rB * 32 + ((l16 ^ ((rB >> 1) & 3)) * 8)];
    }
#pragma unroll
    for (int mi = 0; mi < MI; ++mi)
#pragma unroll
      for (int ni = 0; ni < 4; ++ni)
        acc[mi][ni] = __builtin_amdgcn_mfma_f32_16x16x32_bf16(af[mi], bfr[ni], acc[mi][ni], 0, 0, 0);
  }

  if constexpr (MODE == 0) {
    const int which = n0 >> 9;          // block-uniform after W permutation
    const int b = m0 >> 11;
#pragma unroll
    for (int mi = 0; mi < MI; ++mi) {
#pragma unroll
      for (int ni = 0; ni < 4; ++ni) {
        const int n = n0 + waveN * 64 + ni * 16 + l15;
        const int d = n & 63, h = (n >> 6) & 7;
        const int t = (m0 & (T_ - 1)) + waveM * (TM / 2) + mi * 16 + l16 * 4;
        const size_t bh = (size_t)(b * H_ + h);
        if (which == 0) {
          bf16x4 pv;
#pragma unroll
          for (int r = 0; r < 4; ++r) pv[r] = (__bf16)(acc[mi][ni][r] * QSCALE);
          *(bf16x4*)&o0[(bh * D_ + d) * T_ + t] = pv;            // q [B,H,D,T]
        } else if (which == 1) {
#pragma unroll
          for (int r = 0; r < 4; ++r)
            o1[(bh * T_ + t + r) * D_ + d] = (__bf16)acc[mi][ni][r];  // k [B,H,T,D]
        } else {
          bf16x4 pv;
#pragma unroll
          for (int r = 0; r < 4; ++r) pv[r] = (__bf16)acc[mi][ni][r];
          *(bf16x4*)&o2[(bh * D_ + d) * T_ + t] = pv;            // v [B,H,D,T]
        }
      }
    }
  } else {
#pragma unroll
    for (int mi = 0; mi < MI; ++mi)
#pragma unroll
      for (int ni = 0; ni < 4; ++ni)
#pragma unroll
        for (int r = 0; r < 4; ++r) {
          const int m = m0 + waveM * (TM / 2) + mi * 16 + l16 * 4 + r;
          const int n = n0 + waveN * 64 + ni * 16 + l15;
          of[(size_t)m * N + n] = acc[mi][ni][r];
        }
  }
}

// Flash attention, max-free exp2-domain. R4 compute structure (16x16x32 MFMA,
// Ps LDS transpose, barrier per 2 tiles) but V NEVER TOUCHES LDS:
//  - LDS traffic per kt-instance was 80 KB (staging 16 + frag reads 48 +
//    Ps writes 16) ~= the measured wall at CU LDS throughput -> LDS-BW-bound.
//  - V's fragment pattern V[d=nd*16+l15][t0k+(tw*4+l16)*8 .. +7] is a clean
//    global b128 load (16 rows x 64 contiguous B per instr), and V is L2/L3
//    resident (re-read 16x per bh, 8 MB total). So V goes global->VGPR with a
//    2-set register buffer prefetched ONE FULL PHASE ahead: issued right after
//    the phase barrier, drained by the next phase's waitcnt(0) -> no exposed
//    latency. K keeps the 4-slot gload_lds ring (32 KB). -30% LDS bytes.
// Waves 2x2 over (t-half 32, q-half 64). Ps chunk-XOR swizzled as before.
__global__ __launch_bounds__(256, 2)
void attn_kernel(const __bf16* __restrict__ Q, const __bf16* __restrict__ Kk,
                 const __bf16* __restrict__ Vt, __bf16* __restrict__ Out) {
  __shared__ __align__(16) char smem[49152];
  // K ring[4]:  0, 8192, 16384, 24576   ([64 t][64 d] swizzled granules)
  // Ps: 32768, per-wave [64 q][32 t] chunk-swizzled bf16 (4096 B each, 4 waves).
  float* Osh = (float*)smem;               // overlay: [2 q2][64 d][68] f32 (34816 B)
  float* Lsh = (float*)(smem + 34816);     // overlay: [2 q2][64 q'] f32

  const int tid = threadIdx.x, wave = tid >> 6, lane = tid & 63;
  const int l15 = lane & 15, l16 = lane >> 4;
  const int tw = wave >> 1, q2 = wave & 1;
  const int bh  = blockIdx.y;
  const int t0q = blockIdx.x * 128;
  const __bf16* qptr = Q  + (size_t)bh * D_ * T_;   // [D][T], pre-scaled
  const __bf16* kptr = Kk + (size_t)bh * T_ * D_;   // [T][D]
  const __bf16* vptr = Vt + (size_t)bh * D_ * T_;   // [D][T]

  __bf16* Pw = (__bf16*)(smem + 32768) + wave * 2048;   // [64 q][32 t] swizzled
  const int psw = (l15 >> 1) & 3;                       // per-lane chunk XOR key

  // Q fragments (wave's 64 q-cols), from [d][t]: one-time scalar loads.
  bf16x8 qf[4][2];
#pragma unroll
  for (int ni = 0; ni < 4; ++ni)
#pragma unroll
    for (int ks = 0; ks < 2; ++ks)
#pragma unroll
      for (int j = 0; j < 8; ++j)
        qf[ni][ks][j] = qptr[(size_t)(ks * 32 + l16 * 8 + j) * T_ +
                             t0q + q2 * 64 + ni * 16 + l15];

  bf16x8 ones;
#pragma unroll
  for (int j = 0; j < 8; ++j) ones[j] = (__bf16)1.0f;

  f32x4 oacc[4][4] = {};
  f32x4 lacc[4] = {};

  const int srow = lane >> 3;
  const int sch  = (lane & 7) ^ srow;

  auto stageK = [&](int buf, int t0k) {
    __bf16* Kd = (__bf16*)(smem + buf * 8192);
#pragma unroll
    for (int i = 0; i < 2; ++i) {
      const int row = i * 32 + wave * 8;
      async_ld16(kptr + (size_t)(t0k + row + srow) * D_ + sch * 8, Kd + row * 64);
    }
  };

  // V fragment base: lane covers V[d = nd*16 + l15][t = t0k + (tw*4+l16)*8 ..+7]
  const __bf16* vbase = vptr + (size_t)l15 * T_ + (tw * 4 + l16) * 8;

  bf16x8 vg[2][2][4];                     // [set][tile-in-phase][nd]
  auto loadV = [&](int s, int t0k2) {     // tiles t0k2 and t0k2+64 into set s
#pragma unroll
    for (int kk = 0; kk < 2; ++kk)
#pragma unroll
      for (int nd = 0; nd < 4; ++nd)
        vg[s][kk][nd] = *(const bf16x8*)&vbase[(size_t)nd * 16 * T_ + t0k2 + kk * 64];
  };

  // prologue: first two K tiles staged + first phase's V in flight
  stageK(0, 0);
  stageK(1, 64);
  loadV(0, 0);
#pragma unroll 2
  for (int p = 0; p < 16; ++p) {
    __builtin_amdgcn_s_waitcnt(0);
    __syncthreads();
    if (p < 15) {
      stageK((2 * p + 2) & 3, (2 * p + 2) * 64);
      stageK((2 * p + 3) & 3, (2 * p + 3) * 64);
      loadV((p + 1) & 1, (2 * p + 2) * 64);   // next phase's V, drained at next barrier
    }
#pragma unroll
    for (int kk = 0; kk < 2; ++kk) {
      const int kt = 2 * p + kk;
      const __bf16* Ksc = (const __bf16*)(smem + (kt & 3) * 8192);

      // S^T[t'][q'] over wave's 32 t x 64 q (log2 domain via QSCALE)
      f32x4 sacc[2][4] = {};
#pragma unroll
      for (int ks = 0; ks < 2; ++ks) {
        bf16x8 kf[2];
        const int cb = ks * 4 + l16;
#pragma unroll
        for (int mi = 0; mi < 2; ++mi) {
          const int rt = tw * 32 + mi * 16 + l15;
          kf[mi] = *(const bf16x8*)&Ksc[rt * 64 + ((cb ^ (rt & 7)) * 8)];
        }
#pragma unroll
        for (int mi = 0; mi < 2; ++mi)
#pragma unroll
          for (int ni = 0; ni < 4; ++ni)
            sacc[mi][ni] = __builtin_amdgcn_mfma_f32_16x16x32_bf16(kf[mi], qf[ni][ks], sacc[mi][ni], 0, 0, 0);
      }

      // P = exp2(S) -> wave-private Ps, chunk-swizzled.
      // t = mi*16 + l16*4 + r  ->  chunk = mi*2 + (l16>>1), intra = (l16&1)*4 + r
#pragma unroll
      for (int ni = 0; ni < 4; ++ni)
#pragma unroll
        for (int mi = 0; mi < 2; ++mi) {
          bf16x4 pv;
#pragma unroll
          for (int r = 0; r < 4; ++r) pv[r] = (__bf16)__builtin_amdgcn_exp2f(sacc[mi][ni][r]);
          *(bf16x4*)&Pw[(ni * 16 + l15) * 32 +
                        (((mi * 2 + (l16 >> 1)) ^ psw) * 8) + (l16 & 1) * 4] = pv;
        }

      // O += P*V over wave's 32 t ; l += P*1   (V from registers)
      // A-frag read: t = l16*8 + j -> chunk = l16, intra = j
      {
        bf16x8 pf[4];
#pragma unroll
        for (int mq = 0; mq < 4; ++mq)
          pf[mq] = *(const bf16x8*)&Pw[(mq * 16 + l15) * 32 + ((l16 ^ psw) * 8)];
#pragma unroll
        for (int mq = 0; mq < 4; ++mq) {
#pragma unroll
          for (int nd = 0; nd < 4; ++nd)
            oacc[mq][nd] = __builtin_amdgcn_mfma_f32_16x16x32_bf16(pf[mq], vg[p & 1][kk][nd], oacc[mq][nd], 0, 0, 0);
          lacc[mq] = __builtin_amdgcn_mfma_f32_16x16x32_bf16(pf[mq], ones, lacc[mq], 0, 0, 0);
        }
      }
    }
  }

  // reduce O,l across t-halves; epilogue O/l -> [B,T,H*D] bf16
  __syncthreads();
  if (tw == 1) {
    float* Ow = Osh + q2 * 4352;            // [64 d][68] f32
#pragma unroll
    for (int mq = 0; mq < 4; ++mq)
#pragma unroll
      for (int nd = 0; nd < 4; ++nd)
        *(f32x4*)&Ow[(nd * 16 + l15) * 68 + mq * 16 + l16 * 4] = oacc[mq][nd];
    if (l15 == 0)
#pragma unroll
      for (int mq = 0; mq < 4; ++mq)
        *(f32x4*)&Lsh[q2 * 64 + mq * 16 + l16 * 4] = lacc[mq];
  }
  __syncthreads();
  if (tw == 0) {
    const int b = bh >> 3, hcol = (bh & 7) * D_;
    float* Ow = Osh + q2 * 4352;
#pragma unroll
    for (int mq = 0; mq < 4; ++mq) {
      const f32x4 lv = *(const f32x4*)&Lsh[q2 * 64 + mq * 16 + l16 * 4];
      f32x4 linv;
#pragma unroll
      for (int r = 0; r < 4; ++r) linv[r] = __builtin_amdgcn_rcpf(lacc[mq][r] + lv[r]);
#pragma unroll
      for (int nd = 0; nd < 4; ++nd) {
        const f32x4 op = *(const f32x4*)&Ow[(nd * 16 + l15) * 68 + mq * 16 + l16 * 4];
#pragma unroll
        for (int r = 0; r < 4; ++r) {
          const int trow = t0q + q2 * 64 + mq * 16 + l16 * 4 + r;
          Out[((size_t)b * T_ + trow) * E_ + hcol + nd * 16 + l15] =
              (__bf16)((oacc[mq][nd][r] + op[r]) * linv[r]);
        }
      }
    }
  }
}

extern "C" void kernel_launch(void* const* d_in, const int* in_sizes, int n_in,
                              void* d_out, int out_size, void* d_ws, size_t ws_size,
                              hipStream_t stream) {
  const float* x    = (const float*)d_in[0];
  const float* Wqkv = (const float*)d_in[1];
  const float* W0   = (const float*)d_in[2];
  float* out = (float*)d_out;

  char* ws = (char*)d_ws;
  __bf16* xb  = (__bf16*)ws;                                    // 8192*512 bf16
  __bf16* wqb = (__bf16*)(ws + 8388608);                        // 1536*512 (permuted)
  __bf16* w0b = (__bf16*)(ws + 8388608 + 1572864);              // 512*512
  __bf16* q   = (__bf16*)(ws + 8388608 + 1572864 + 524288);     // [B,H,D,T]
  __bf16* k   = q + 4194304;                                    // [B,H,T,D]
  __bf16* v   = k + 4194304;                                    // [B,H,D,T]
  __bf16* ao  = xb;  // reuse: xb consumed by QKV GEMM before attn writes ao

  cvt_all<<<2560, 256, 0, stream>>>(x, Wqkv, W0, xb, wqb, w0b);
  gemm_bt<0, 3 * H_ * D_, 128><<<dim3(12, 64), 256, 0, stream>>>(xb, wqb, q, k, v, nullptr);
  attn_kernel<<<dim3(16, 32), 256, 0, stream>>>(q, k, v, ao);
  gemm_bt<1, E_, 64><<<dim3(4, 128), 256, 0, stream>>>(ao, w0b, nullptr, nullptr, nullptr, out);
}

// Round 8
// 167.697 us; speedup vs baseline: 1.3213x; 1.3213x over previous
//
#include <hip/hip_runtime.h>

typedef __bf16 bf16x8 __attribute__((ext_vector_type(8)));
typedef __bf16 bf16x4 __attribute__((ext_vector_type(4)));
typedef float  f32x4  __attribute__((ext_vector_type(4)));

#define B_ 4
#define T_ 2048
#define H_ 8
#define D_ 64
#define E_ 512

// q scale: D^-0.5 * log2(e)  (softmax computed in exp2 domain)
#define QSCALE 0.18033688011112042f

// async global->LDS, 16B per lane. LDS dest is wave-uniform base + lane*16.
__device__ __forceinline__ void async_ld16(const __bf16* g, __bf16* lds) {
  __builtin_amdgcn_global_load_lds((const __attribute__((address_space(1))) void*)g,
                                   (__attribute__((address_space(3))) void*)lds,
                                   16, 0, 0);
}

// converts x, W_qkv (row-permuted to [which][h][d] order), W_0
__global__ void cvt_all(const float* __restrict__ x, const float* __restrict__ wq,
                        const float* __restrict__ w0, __bf16* __restrict__ xb,
                        __bf16* __restrict__ wqb, __bf16* __restrict__ w0b) {
  long i = (long)(blockIdx.x * 256 + threadIdx.x) * 8;
  const float* src; __bf16* dst; long roff, woff;
  if (i < 4194304L)      { src = x;  dst = xb;  roff = i; woff = i; }
  else if (i < 4980736L) {
    src = wq; dst = wqb; roff = i - 4194304L;
    // src row r = h*192 + d*3 + which  ->  dst row = which*512 + h*64 + d
    const int r = (int)(roff >> 9), c = (int)(roff & 511);
    const int h = r / 192, rem = r - h * 192;
    const int d = rem / 3, which = rem - d * 3;
    woff = (long)(which * 512 + h * 64 + d) * 512 + c;
  }
  else                   { src = w0; dst = w0b; roff = i - 4980736L; woff = roff; }
  float4 a = *(const float4*)(src + roff);
  float4 b = *(const float4*)(src + roff + 4);
  bf16x8 o;
  o[0] = (__bf16)a.x; o[1] = (__bf16)a.y; o[2] = (__bf16)a.z; o[3] = (__bf16)a.w;
  o[4] = (__bf16)b.x; o[5] = (__bf16)b.y; o[6] = (__bf16)b.z; o[7] = (__bf16)b.w;
  *(bf16x8*)(dst + woff) = o;
}

// C = A(MxK) * B(NxK)^T, K=512, TMx128 tile, 4 waves, 16x16x32 bf16 MFMA.
// BK=32, 3-slot LDS ring, prefetch depth 2, counted vmcnt (T3/T4).
// MODE 0 (TM=128): qkv epilogue (W pre-permuted -> which = n0>>9 block-uniform).
// MODE 1: plain fp32 store, row-major MxN.
template<int MODE, int N, int TM>
__global__ __launch_bounds__(256, TM == 128 ? 3 : 4)
void gemm_bt(const __bf16* __restrict__ A, const __bf16* __restrict__ Bm,
             __bf16* __restrict__ o0, __bf16* __restrict__ o1, __bf16* __restrict__ o2,
             float* __restrict__ of) {
  constexpr int K = 512;
  constexpr int MI = TM / 32;                 // acc tiles in m per wave
  constexpr int AL = TM / 64;                 // A slab-loads per wave per stage
  __shared__ __bf16 As[3][TM * 32];
  __shared__ __bf16 Bs[3][128 * 32];
  const int tid  = threadIdx.x;
  const int wave = tid >> 6, lane = tid & 63;
  const int l15 = lane & 15, l16 = lane >> 4;
  const int m0 = blockIdx.y * TM, n0 = blockIdx.x * 128;
  const int waveM = wave >> 1, waveN = wave & 1;
  // staging lane map: 16-row slab of 32 cols (64 B/row); lane -> (row, chunk)
  const int lr  = lane >> 2;
  const int lc8 = ((lane & 3) ^ ((lane >> 3) & 3)) * 8;

  f32x4 acc[MI][4] = {};

  const __bf16* ag = A  + (size_t)(m0 + wave * (AL * 16) + lr) * K + lc8;
  const __bf16* bg = Bm + (size_t)(n0 + wave * 32 + lr) * K + lc8;

  auto stage = [&](int buf, int k0) {
#pragma unroll
    for (int it = 0; it < AL; ++it)
      async_ld16(ag + (size_t)it * 16 * K + k0, &As[buf][(wave * AL + it) * 512]);
#pragma unroll
    for (int it = 0; it < 2; ++it)
      async_ld16(bg + (size_t)it * 16 * K + k0, &Bs[buf][(wave * 2 + it) * 512]);
  };

  stage(0, 0);
  stage(1, 32);
#pragma unroll
  for (int s = 0; s < 16; ++s) {
    if (s == 15) {
      asm volatile("s_waitcnt vmcnt(0)" ::: "memory");
    } else {
      if constexpr (AL == 2) asm volatile("s_waitcnt vmcnt(4)" ::: "memory");
      else                   asm volatile("s_waitcnt vmcnt(3)" ::: "memory");
    }
    __builtin_amdgcn_s_barrier();
    if (s < 14) stage((s + 2) % 3, (s + 2) * 32);
    const __bf16* Ac = As[s % 3];
    const __bf16* Bc = Bs[s % 3];
    bf16x8 af[MI], bfr[4];
#pragma unroll
    for (int i = 0; i < MI; ++i) {
      const int rA = waveM * (TM / 2) + i * 16 + l15;
      af[i] = *(const bf16x8*)&Ac[rA * 32 + ((l16 ^ ((rA >> 1) & 3)) * 8)];
    }
#pragma unroll
    for (int i = 0; i < 4; ++i) {
      const int rB = waveN * 64 + i * 16 + l15;
      bfr[i] = *(const bf16x8*)&Bc[rB * 32 + ((l16 ^ ((rB >> 1) & 3)) * 8)];
    }
#pragma unroll
    for (int mi = 0; mi < MI; ++mi)
#pragma unroll
      for (int ni = 0; ni < 4; ++ni)
        acc[mi][ni] = __builtin_amdgcn_mfma_f32_16x16x32_bf16(af[mi], bfr[ni], acc[mi][ni], 0, 0, 0);
  }

  if constexpr (MODE == 0) {
    const int which = n0 >> 9;          // block-uniform after W permutation
    const int b = m0 >> 11;
#pragma unroll
    for (int mi = 0; mi < MI; ++mi) {
#pragma unroll
      for (int ni = 0; ni < 4; ++ni) {
        const int n = n0 + waveN * 64 + ni * 16 + l15;
        const int d = n & 63, h = (n >> 6) & 7;
        const int t = (m0 & (T_ - 1)) + waveM * (TM / 2) + mi * 16 + l16 * 4;
        const size_t bh = (size_t)(b * H_ + h);
        if (which == 0) {
          bf16x4 pv;
#pragma unroll
          for (int r = 0; r < 4; ++r) pv[r] = (__bf16)(acc[mi][ni][r] * QSCALE);
          *(bf16x4*)&o0[(bh * D_ + d) * T_ + t] = pv;            // q [B,H,D,T]
        } else if (which == 1) {
#pragma unroll
          for (int r = 0; r < 4; ++r)
            o1[(bh * T_ + t + r) * D_ + d] = (__bf16)acc[mi][ni][r];  // k [B,H,T,D]
        } else {
          bf16x4 pv;
#pragma unroll
          for (int r = 0; r < 4; ++r) pv[r] = (__bf16)acc[mi][ni][r];
          *(bf16x4*)&o2[(bh * D_ + d) * T_ + t] = pv;            // v [B,H,D,T]
        }
      }
    }
  } else {
#pragma unroll
    for (int mi = 0; mi < MI; ++mi)
#pragma unroll
      for (int ni = 0; ni < 4; ++ni)
#pragma unroll
        for (int r = 0; r < 4; ++r) {
          const int m = m0 + waveM * (TM / 2) + mi * 16 + l16 * 4 + r;
          const int n = n0 + waveN * 64 + ni * 16 + l15;
          of[(size_t)m * N + n] = acc[mi][ni][r];
        }
  }
}

// Flash attention, max-free exp2-domain. R4 compute structure (16x16x32 MFMA,
// Ps LDS transpose, barrier per 2 tiles) with V IN REGISTERS, static-index
// edition (R7 post-mortem: runtime-indexed V buffer spilled to scratch,
// WRITE_SIZE 268 MB — rule #20). Here the phase loop is 8 x (even,odd) so
// every K-ring slot is a compile-time constant, and the V double-buffer is
// two NAMED arrays (vgA/vgB) only ever accessed through fully-unrolled
// macro loops. V frag pattern V[d=nd*16+l15][t0k+(tw*4+l16)*8..+7] is a
// clean global b128 (V is L2/L3-resident); loads are issued one full phase
// ahead (right after the barrier) and drained by the next phase's
// waitcnt(0) -> no exposed latency. K keeps the 4-slot gload_lds ring.
// LDS bytes/kt-instance drop ~30% (no V staging, no V LDS reads).
__global__ __launch_bounds__(256, 2)
void attn_kernel(const __bf16* __restrict__ Q, const __bf16* __restrict__ Kk,
                 const __bf16* __restrict__ Vt, __bf16* __restrict__ Out) {
  __shared__ __align__(16) char smem[49152];
  // K ring[4]:  0, 8192, 16384, 24576   ([64 t][64 d] swizzled granules)
  // Ps: 32768, per-wave [64 q][32 t] chunk-swizzled bf16 (4096 B each, 4 waves).
  float* Osh = (float*)smem;               // overlay: [2 q2][64 d][68] f32 (34816 B)
  float* Lsh = (float*)(smem + 34816);     // overlay: [2 q2][64 q'] f32

  const int tid = threadIdx.x, wave = tid >> 6, lane = tid & 63;
  const int l15 = lane & 15, l16 = lane >> 4;
  const int tw = wave >> 1, q2 = wave & 1;
  const int bh  = blockIdx.y;
  const int t0q = blockIdx.x * 128;
  const __bf16* qptr = Q  + (size_t)bh * D_ * T_;   // [D][T], pre-scaled
  const __bf16* kptr = Kk + (size_t)bh * T_ * D_;   // [T][D]
  const __bf16* vptr = Vt + (size_t)bh * D_ * T_;   // [D][T]

  __bf16* Pw = (__bf16*)(smem + 32768) + wave * 2048;   // [64 q][32 t] swizzled
  const int psw = (l15 >> 1) & 3;                       // per-lane chunk XOR key

  // Q fragments (wave's 64 q-cols), from [d][t]: one-time scalar loads.
  bf16x8 qf[4][2];
#pragma unroll
  for (int ni = 0; ni < 4; ++ni)
#pragma unroll
    for (int ks = 0; ks < 2; ++ks)
#pragma unroll
      for (int j = 0; j < 8; ++j)
        qf[ni][ks][j] = qptr[(size_t)(ks * 32 + l16 * 8 + j) * T_ +
                             t0q + q2 * 64 + ni * 16 + l15];

  bf16x8 ones;
#pragma unroll
  for (int j = 0; j < 8; ++j) ones[j] = (__bf16)1.0f;

  f32x4 oacc[4][4] = {};
  f32x4 lacc[4] = {};

  const int srow = lane >> 3;
  const int sch  = (lane & 7) ^ srow;

  auto stageK = [&](int buf, int t0k) {
    __bf16* Kd = (__bf16*)(smem + buf * 8192);
#pragma unroll
    for (int i = 0; i < 2; ++i) {
      const int row = i * 32 + wave * 8;
      async_ld16(kptr + (size_t)(t0k + row + srow) * D_ + sch * 8, Kd + row * 64);
    }
  };

  // V fragment base: lane covers V[d = nd*16 + l15][t = t0k + (tw*4+l16)*8 ..+7]
  const __bf16* vbase = vptr + (size_t)l15 * T_ + (tw * 4 + l16) * 8;

  bf16x8 vgA[2][4];   // V frags for tiles of the EVEN phase (static names!)
  bf16x8 vgB[2][4];   // V frags for tiles of the ODD phase

// fully-unrolled, static-index V load: tiles (t0k2) and (t0k2 + 64)
#define LOADV(vg, t0k2)                                                        \
  {                                                                            \
    _Pragma("unroll") for (int kk = 0; kk < 2; ++kk)                           \
      _Pragma("unroll") for (int nd = 0; nd < 4; ++nd)                         \
        vg[kk][nd] = *(const bf16x8*)&vbase[(size_t)nd * 16 * T_ +             \
                                            (size_t)((t0k2) + kk * 64)];       \
  }

// one kt tile: QK^T (K from LDS slot KSLOT) -> exp2 -> Ps -> PV (V frags VF)
#define TILE(KSLOT, VF)                                                        \
  {                                                                            \
    const __bf16* Ksc = (const __bf16*)(smem + (KSLOT) * 8192);                \
    f32x4 sacc[2][4] = {};                                                     \
    _Pragma("unroll") for (int ks = 0; ks < 2; ++ks) {                         \
      bf16x8 kf[2];                                                            \
      const int cb = ks * 4 + l16;                                             \
      _Pragma("unroll") for (int mi = 0; mi < 2; ++mi) {                       \
        const int rt = tw * 32 + mi * 16 + l15;                                \
        kf[mi] = *(const bf16x8*)&Ksc[rt * 64 + ((cb ^ (rt & 7)) * 8)];        \
      }                                                                        \
      _Pragma("unroll") for (int mi = 0; mi < 2; ++mi)                         \
        _Pragma("unroll") for (int ni = 0; ni < 4; ++ni)                       \
          sacc[mi][ni] = __builtin_amdgcn_mfma_f32_16x16x32_bf16(              \
              kf[mi], qf[ni][ks], sacc[mi][ni], 0, 0, 0);                      \
    }                                                                          \
    _Pragma("unroll") for (int ni = 0; ni < 4; ++ni)                           \
      _Pragma("unroll") for (int mi = 0; mi < 2; ++mi) {                       \
        bf16x4 pv;                                                             \
        _Pragma("unroll") for (int r = 0; r < 4; ++r)                          \
          pv[r] = (__bf16)__builtin_amdgcn_exp2f(sacc[mi][ni][r]);             \
        *(bf16x4*)&Pw[(ni * 16 + l15) * 32 +                                   \
                      (((mi * 2 + (l16 >> 1)) ^ psw) * 8) + (l16 & 1) * 4] = pv;\
      }                                                                        \
    {                                                                          \
      bf16x8 pf[4];                                                            \
      _Pragma("unroll") for (int mq = 0; mq < 4; ++mq)                         \
        pf[mq] = *(const bf16x8*)&Pw[(mq * 16 + l15) * 32 + ((l16 ^ psw) * 8)];\
      _Pragma("unroll") for (int mq = 0; mq < 4; ++mq) {                       \
        _Pragma("unroll") for (int nd = 0; nd < 4; ++nd)                       \
          oacc[mq][nd] = __builtin_amdgcn_mfma_f32_16x16x32_bf16(              \
              pf[mq], VF[nd], oacc[mq][nd], 0, 0, 0);                          \
        lacc[mq] = __builtin_amdgcn_mfma_f32_16x16x32_bf16(                    \
            pf[mq], ones, lacc[mq], 0, 0, 0);                                  \
      }                                                                        \
    }                                                                          \
  }

  // prologue: tiles 0,1 staged to K slots 0,1; their V frags into vgA
  stageK(0, 0);
  stageK(1, 64);
  LOADV(vgA, 0)
#pragma unroll 1
  for (int pp = 0; pp < 8; ++pp) {
    const int t4 = pp * 256;             // t0k of tile 4*pp
    // ---- even phase: compute tiles 4pp,4pp+1 (slots 0,1; V=vgA) ----
    __builtin_amdgcn_s_waitcnt(0);
    __syncthreads();
    stageK(2, t4 + 128);                 // tile 4pp+2 -> slot 2
    stageK(3, t4 + 192);                 // tile 4pp+3 -> slot 3
    LOADV(vgB, t4 + 128)                 // V for odd phase
    TILE(0, vgA[0])
    TILE(1, vgA[1])
    // ---- odd phase: compute tiles 4pp+2,4pp+3 (slots 2,3; V=vgB) ----
    __builtin_amdgcn_s_waitcnt(0);
    __syncthreads();
    if (pp < 7) {
      stageK(0, t4 + 256);               // tile 4pp+4 -> slot 0
      stageK(1, t4 + 320);               // tile 4pp+5 -> slot 1
      LOADV(vgA, t4 + 256)               // V for next even phase
    }
    TILE(2, vgB[0])
    TILE(3, vgB[1])
  }
#undef LOADV
#undef TILE

  // reduce O,l across t-halves; epilogue O/l -> [B,T,H*D] bf16
  __syncthreads();
  if (tw == 1) {
    float* Ow = Osh + q2 * 4352;            // [64 d][68] f32
#pragma unroll
    for (int mq = 0; mq < 4; ++mq)
#pragma unroll
      for (int nd = 0; nd < 4; ++nd)
        *(f32x4*)&Ow[(nd * 16 + l15) * 68 + mq * 16 + l16 * 4] = oacc[mq][nd];
    if (l15 == 0)
#pragma unroll
      for (int mq = 0; mq < 4; ++mq)
        *(f32x4*)&Lsh[q2 * 64 + mq * 16 + l16 * 4] = lacc[mq];
  }
  __syncthreads();
  if (tw == 0) {
    const int b = bh >> 3, hcol = (bh & 7) * D_;
    float* Ow = Osh + q2 * 4352;
#pragma unroll
    for (int mq = 0; mq < 4; ++mq) {
      const f32x4 lv = *(const f32x4*)&Lsh[q2 * 64 + mq * 16 + l16 * 4];
      f32x4 linv;
#pragma unroll
      for (int r = 0; r < 4; ++r) linv[r] = __builtin_amdgcn_rcpf(lacc[mq][r] + lv[r]);
#pragma unroll
      for (int nd = 0; nd < 4; ++nd) {
        const f32x4 op = *(const f32x4*)&Ow[(nd * 16 + l15) * 68 + mq * 16 + l16 * 4];
#pragma unroll
        for (int r = 0; r < 4; ++r) {
          const int trow = t0q + q2 * 64 + mq * 16 + l16 * 4 + r;
          Out[((size_t)b * T_ + trow) * E_ + hcol + nd * 16 + l15] =
              (__bf16)((oacc[mq][nd][r] + op[r]) * linv[r]);
        }
      }
    }
  }
}

extern "C" void kernel_launch(void* const* d_in, const int* in_sizes, int n_in,
                              void* d_out, int out_size, void* d_ws, size_t ws_size,
                              hipStream_t stream) {
  const float* x    = (const float*)d_in[0];
  const float* Wqkv = (const float*)d_in[1];
  const float* W0   = (const float*)d_in[2];
  float* out = (float*)d_out;

  char* ws = (char*)d_ws;
  __bf16* xb  = (__bf16*)ws;                                    // 8192*512 bf16
  __bf16* wqb = (__bf16*)(ws + 8388608);                        // 1536*512 (permuted)
  __bf16* w0b = (__bf16*)(ws + 8388608 + 1572864);              // 512*512
  __bf16* q   = (__bf16*)(ws + 8388608 + 1572864 + 524288);     // [B,H,D,T]
  __bf16* k   = q + 4194304;                                    // [B,H,T,D]
  __bf16* v   = k + 4194304;                                    // [B,H,D,T]
  __bf16* ao  = xb;  // reuse: xb consumed by QKV GEMM before attn writes ao

  cvt_all<<<2560, 256, 0, stream>>>(x, Wqkv, W0, xb, wqb, w0b);
  gemm_bt<0, 3 * H_ * D_, 128><<<dim3(12, 64), 256, 0, stream>>>(xb, wqb, q, k, v, nullptr);
  attn_kernel<<<dim3(16, 32), 256, 0, stream>>>(q, k, v, ao);
  gemm_bt<1, E_, 64><<<dim3(4, 128), 256, 0, stream>>>(ao, w0b, nullptr, nullptr, nullptr, out);
}

// Round 9
// 159.206 us; speedup vs baseline: 1.3918x; 1.0533x over previous
//
#include <hip/hip_runtime.h>

typedef __bf16 bf16x8 __attribute__((ext_vector_type(8)));
typedef __bf16 bf16x4 __attribute__((ext_vector_type(4)));
typedef float  f32x4  __attribute__((ext_vector_type(4)));

#define B_ 4
#define T_ 2048
#define H_ 8
#define D_ 64
#define E_ 512

// q scale: D^-0.5 * log2(e)  (softmax computed in exp2 domain)
#define QSCALE 0.18033688011112042f

// async global->LDS, 16B per lane. LDS dest is wave-uniform base + lane*16.
__device__ __forceinline__ void async_ld16(const __bf16* g, __bf16* lds) {
  __builtin_amdgcn_global_load_lds((const __attribute__((address_space(1))) void*)g,
                                   (__attribute__((address_space(3))) void*)lds,
                                   16, 0, 0);
}

// converts x, W_qkv (row-permuted to [which][h][d] order), W_0
__global__ void cvt_all(const float* __restrict__ x, const float* __restrict__ wq,
                        const float* __restrict__ w0, __bf16* __restrict__ xb,
                        __bf16* __restrict__ wqb, __bf16* __restrict__ w0b) {
  long i = (long)(blockIdx.x * 256 + threadIdx.x) * 8;
  const float* src; __bf16* dst; long roff, woff;
  if (i < 4194304L)      { src = x;  dst = xb;  roff = i; woff = i; }
  else if (i < 4980736L) {
    src = wq; dst = wqb; roff = i - 4194304L;
    // src row r = h*192 + d*3 + which  ->  dst row = which*512 + h*64 + d
    const int r = (int)(roff >> 9), c = (int)(roff & 511);
    const int h = r / 192, rem = r - h * 192;
    const int d = rem / 3, which = rem - d * 3;
    woff = (long)(which * 512 + h * 64 + d) * 512 + c;
  }
  else                   { src = w0; dst = w0b; roff = i - 4980736L; woff = roff; }
  float4 a = *(const float4*)(src + roff);
  float4 b = *(const float4*)(src + roff + 4);
  bf16x8 o;
  o[0] = (__bf16)a.x; o[1] = (__bf16)a.y; o[2] = (__bf16)a.z; o[3] = (__bf16)a.w;
  o[4] = (__bf16)b.x; o[5] = (__bf16)b.y; o[6] = (__bf16)b.z; o[7] = (__bf16)b.w;
  *(bf16x8*)(dst + woff) = o;
}

// C = A(MxK) * B(NxK)^T, K=512, TMx128 tile, 4 waves, 16x16x32 bf16 MFMA.
// BK=32, 3-slot LDS ring, prefetch depth 2, counted vmcnt (T3/T4).
// MODE 0 (TM=128): qkv epilogue (W pre-permuted -> which = n0>>9 block-uniform).
// MODE 1: plain fp32 store, row-major MxN.
template<int MODE, int N, int TM>
__global__ __launch_bounds__(256, TM == 128 ? 3 : 4)
void gemm_bt(const __bf16* __restrict__ A, const __bf16* __restrict__ Bm,
             __bf16* __restrict__ o0, __bf16* __restrict__ o1, __bf16* __restrict__ o2,
             float* __restrict__ of) {
  constexpr int K = 512;
  constexpr int MI = TM / 32;                 // acc tiles in m per wave
  constexpr int AL = TM / 64;                 // A slab-loads per wave per stage
  __shared__ __bf16 As[3][TM * 32];
  __shared__ __bf16 Bs[3][128 * 32];
  const int tid  = threadIdx.x;
  const int wave = tid >> 6, lane = tid & 63;
  const int l15 = lane & 15, l16 = lane >> 4;
  const int m0 = blockIdx.y * TM, n0 = blockIdx.x * 128;
  const int waveM = wave >> 1, waveN = wave & 1;
  // staging lane map: 16-row slab of 32 cols (64 B/row); lane -> (row, chunk)
  const int lr  = lane >> 2;
  const int lc8 = ((lane & 3) ^ ((lane >> 3) & 3)) * 8;

  f32x4 acc[MI][4] = {};

  const __bf16* ag = A  + (size_t)(m0 + wave * (AL * 16) + lr) * K + lc8;
  const __bf16* bg = Bm + (size_t)(n0 + wave * 32 + lr) * K + lc8;

  auto stage = [&](int buf, int k0) {
#pragma unroll
    for (int it = 0; it < AL; ++it)
      async_ld16(ag + (size_t)it * 16 * K + k0, &As[buf][(wave * AL + it) * 512]);
#pragma unroll
    for (int it = 0; it < 2; ++it)
      async_ld16(bg + (size_t)it * 16 * K + k0, &Bs[buf][(wave * 2 + it) * 512]);
  };

  stage(0, 0);
  stage(1, 32);
#pragma unroll
  for (int s = 0; s < 16; ++s) {
    if (s == 15) {
      asm volatile("s_waitcnt vmcnt(0)" ::: "memory");
    } else {
      if constexpr (AL == 2) asm volatile("s_waitcnt vmcnt(4)" ::: "memory");
      else                   asm volatile("s_waitcnt vmcnt(3)" ::: "memory");
    }
    __builtin_amdgcn_s_barrier();
    if (s < 14) stage((s + 2) % 3, (s + 2) * 32);
    const __bf16* Ac = As[s % 3];
    const __bf16* Bc = Bs[s % 3];
    bf16x8 af[MI], bfr[4];
#pragma unroll
    for (int i = 0; i < MI; ++i) {
      const int rA = waveM * (TM / 2) + i * 16 + l15;
      af[i] = *(const bf16x8*)&Ac[rA * 32 + ((l16 ^ ((rA >> 1) & 3)) * 8)];
    }
#pragma unroll
    for (int i = 0; i < 4; ++i) {
      const int rB = waveN * 64 + i * 16 + l15;
      bfr[i] = *(const bf16x8*)&Bc[rB * 32 + ((l16 ^ ((rB >> 1) & 3)) * 8)];
    }
#pragma unroll
    for (int mi = 0; mi < MI; ++mi)
#pragma unroll
      for (int ni = 0; ni < 4; ++ni)
        acc[mi][ni] = __builtin_amdgcn_mfma_f32_16x16x32_bf16(af[mi], bfr[ni], acc[mi][ni], 0, 0, 0);
  }

  if constexpr (MODE == 0) {
    const int which = n0 >> 9;          // block-uniform after W permutation
    const int b = m0 >> 11;
#pragma unroll
    for (int mi = 0; mi < MI; ++mi) {
#pragma unroll
      for (int ni = 0; ni < 4; ++ni) {
        const int n = n0 + waveN * 64 + ni * 16 + l15;
        const int d = n & 63, h = (n >> 6) & 7;
        const int t = (m0 & (T_ - 1)) + waveM * (TM / 2) + mi * 16 + l16 * 4;
        const size_t bh = (size_t)(b * H_ + h);
        if (which == 0) {
          bf16x4 pv;
#pragma unroll
          for (int r = 0; r < 4; ++r) pv[r] = (__bf16)(acc[mi][ni][r] * QSCALE);
          *(bf16x4*)&o0[(bh * D_ + d) * T_ + t] = pv;            // q [B,H,D,T]
        } else if (which == 1) {
#pragma unroll
          for (int r = 0; r < 4; ++r)
            o1[(bh * T_ + t + r) * D_ + d] = (__bf16)acc[mi][ni][r];  // k [B,H,T,D]
        } else {
          bf16x4 pv;
#pragma unroll
          for (int r = 0; r < 4; ++r) pv[r] = (__bf16)acc[mi][ni][r];
          *(bf16x4*)&o2[(bh * D_ + d) * T_ + t] = pv;            // v [B,H,D,T]
        }
      }
    }
  } else {
#pragma unroll
    for (int mi = 0; mi < MI; ++mi)
#pragma unroll
      for (int ni = 0; ni < 4; ++ni)
#pragma unroll
        for (int r = 0; r < 4; ++r) {
          const int m = m0 + waveM * (TM / 2) + mi * 16 + l16 * 4 + r;
          const int n = n0 + waveN * 64 + ni * 16 + l15;
          of[(size_t)m * N + n] = acc[mi][ni][r];
        }
  }
}

// Flash attention, max-free exp2-domain. R4 compute structure (16x16x32 MFMA,
// Ps LDS transpose, 4-slot K ring, barrier per 2 tiles) with V loaded
// GLOBAL->VGPR PER TILE (no cross-barrier V state — the R7/R8 spill bug was
// a phase-long V double-buffer the allocator refused to keep; here vf is a
// 16-VGPR transient inside each tile). V loads are issued at the TOP of the
// tile; QK^T + exp2 + Ps round-trip (~400-600 cy) hide the L2 latency
// (V is L2-resident: 256 KB/bh re-read 16x). Compiler inserts the counted
// vmcnt before the PV use. Deletes V staging (8 KB/tile LDS writes) and
// V LDS reads (16 KB/tile) from the LDS budget, and the V ds_read latency
// from the PV chain. Waves 2x2 over (t-half 32, q-half 64).
__global__ __launch_bounds__(256, 2)
void attn_kernel(const __bf16* __restrict__ Q, const __bf16* __restrict__ Kk,
                 const __bf16* __restrict__ Vt, __bf16* __restrict__ Out) {
  __shared__ __align__(16) char smem[49152];
  // K ring[4]:  0, 8192, 16384, 24576   ([64 t][64 d] swizzled granules)
  // Ps: 32768, per-wave [64 q][32 t] chunk-swizzled bf16 (4096 B each, 4 waves).
  float* Osh = (float*)smem;               // overlay: [2 q2][64 d][68] f32 (34816 B)
  float* Lsh = (float*)(smem + 34816);     // overlay: [2 q2][64 q'] f32

  const int tid = threadIdx.x, wave = tid >> 6, lane = tid & 63;
  const int l15 = lane & 15, l16 = lane >> 4;
  const int tw = wave >> 1, q2 = wave & 1;
  const int bh  = blockIdx.y;
  const int t0q = blockIdx.x * 128;
  const __bf16* qptr = Q  + (size_t)bh * D_ * T_;   // [D][T], pre-scaled
  const __bf16* kptr = Kk + (size_t)bh * T_ * D_;   // [T][D]
  const __bf16* vptr = Vt + (size_t)bh * D_ * T_;   // [D][T]

  __bf16* Pw = (__bf16*)(smem + 32768) + wave * 2048;   // [64 q][32 t] swizzled
  const int psw = (l15 >> 1) & 3;                       // per-lane chunk XOR key

  // Q fragments (wave's 64 q-cols), from [d][t]: one-time scalar loads.
  bf16x8 qf[4][2];
#pragma unroll
  for (int ni = 0; ni < 4; ++ni)
#pragma unroll
    for (int ks = 0; ks < 2; ++ks)
#pragma unroll
      for (int j = 0; j < 8; ++j)
        qf[ni][ks][j] = qptr[(size_t)(ks * 32 + l16 * 8 + j) * T_ +
                             t0q + q2 * 64 + ni * 16 + l15];

  bf16x8 ones;
#pragma unroll
  for (int j = 0; j < 8; ++j) ones[j] = (__bf16)1.0f;

  f32x4 oacc[4][4] = {};
  f32x4 lacc[4] = {};

  const int srow = lane >> 3;
  const int sch  = (lane & 7) ^ srow;

  auto stageK = [&](int buf, int t0k) {
    __bf16* Kd = (__bf16*)(smem + buf * 8192);
#pragma unroll
    for (int i = 0; i < 2; ++i) {
      const int row = i * 32 + wave * 8;
      async_ld16(kptr + (size_t)(t0k + row + srow) * D_ + sch * 8, Kd + row * 64);
    }
  };

  // V fragment base: lane covers V[d = nd*16 + l15][t = t0k + (tw*4+l16)*8 ..+7]
  const __bf16* vbase = vptr + (size_t)l15 * T_ + (tw * 4 + l16) * 8;

// one kt tile: V global loads issued FIRST (transient 16-VGPR vf, consumed at
// the end of the same tile), then QK^T (K from LDS slot KSLOT) -> exp2 -> Ps
// round-trip -> PV. All indices compile-time constant (rule #20).
#define TILE(KSLOT, T0K)                                                       \
  {                                                                            \
    bf16x8 vf[4];                                                              \
    _Pragma("unroll") for (int nd = 0; nd < 4; ++nd)                           \
      vf[nd] = *(const bf16x8*)&vbase[(size_t)nd * 16 * T_ + (size_t)(T0K)];   \
    const __bf16* Ksc = (const __bf16*)(smem + (KSLOT) * 8192);                \
    f32x4 sacc[2][4] = {};                                                     \
    _Pragma("unroll") for (int ks = 0; ks < 2; ++ks) {                         \
      bf16x8 kf[2];                                                            \
      const int cb = ks * 4 + l16;                                             \
      _Pragma("unroll") for (int mi = 0; mi < 2; ++mi) {                       \
        const int rt = tw * 32 + mi * 16 + l15;                                \
        kf[mi] = *(const bf16x8*)&Ksc[rt * 64 + ((cb ^ (rt & 7)) * 8)];        \
      }                                                                        \
      _Pragma("unroll") for (int mi = 0; mi < 2; ++mi)                         \
        _Pragma("unroll") for (int ni = 0; ni < 4; ++ni)                       \
          sacc[mi][ni] = __builtin_amdgcn_mfma_f32_16x16x32_bf16(              \
              kf[mi], qf[ni][ks], sacc[mi][ni], 0, 0, 0);                      \
    }                                                                          \
    _Pragma("unroll") for (int ni = 0; ni < 4; ++ni)                           \
      _Pragma("unroll") for (int mi = 0; mi < 2; ++mi) {                       \
        bf16x4 pv;                                                             \
        _Pragma("unroll") for (int r = 0; r < 4; ++r)                          \
          pv[r] = (__bf16)__builtin_amdgcn_exp2f(sacc[mi][ni][r]);             \
        *(bf16x4*)&Pw[(ni * 16 + l15) * 32 +                                   \
                      (((mi * 2 + (l16 >> 1)) ^ psw) * 8) + (l16 & 1) * 4] = pv;\
      }                                                                        \
    {                                                                          \
      bf16x8 pf[4];                                                            \
      _Pragma("unroll") for (int mq = 0; mq < 4; ++mq)                         \
        pf[mq] = *(const bf16x8*)&Pw[(mq * 16 + l15) * 32 + ((l16 ^ psw) * 8)];\
      _Pragma("unroll") for (int mq = 0; mq < 4; ++mq) {                       \
        _Pragma("unroll") for (int nd = 0; nd < 4; ++nd)                       \
          oacc[mq][nd] = __builtin_amdgcn_mfma_f32_16x16x32_bf16(              \
              pf[mq], vf[nd], oacc[mq][nd], 0, 0, 0);                          \
        lacc[mq] = __builtin_amdgcn_mfma_f32_16x16x32_bf16(                    \
            pf[mq], ones, lacc[mq], 0, 0, 0);                                  \
      }                                                                        \
    }                                                                          \
  }

  // prologue: K tiles 0,1 staged to slots 0,1
  stageK(0, 0);
  stageK(1, 64);
#pragma unroll 1
  for (int pp = 0; pp < 8; ++pp) {
    const int t4 = pp * 256;             // t0k of tile 4*pp
    // ---- even phase: compute tiles 4pp,4pp+1 (K slots 0,1) ----
    __builtin_amdgcn_s_waitcnt(0);
    __syncthreads();
    stageK(2, t4 + 128);                 // tile 4pp+2 -> slot 2
    stageK(3, t4 + 192);                 // tile 4pp+3 -> slot 3
    TILE(0, t4)
    TILE(1, t4 + 64)
    // ---- odd phase: compute tiles 4pp+2,4pp+3 (K slots 2,3) ----
    __builtin_amdgcn_s_waitcnt(0);
    __syncthreads();
    if (pp < 7) {
      stageK(0, t4 + 256);               // tile 4pp+4 -> slot 0
      stageK(1, t4 + 320);               // tile 4pp+5 -> slot 1
    }
    TILE(2, t4 + 128)
    TILE(3, t4 + 192)
  }
#undef TILE

  // reduce O,l across t-halves; epilogue O/l -> [B,T,H*D] bf16
  __syncthreads();
  if (tw == 1) {
    float* Ow = Osh + q2 * 4352;            // [64 d][68] f32
#pragma unroll
    for (int mq = 0; mq < 4; ++mq)
#pragma unroll
      for (int nd = 0; nd < 4; ++nd)
        *(f32x4*)&Ow[(nd * 16 + l15) * 68 + mq * 16 + l16 * 4] = oacc[mq][nd];
    if (l15 == 0)
#pragma unroll
      for (int mq = 0; mq < 4; ++mq)
        *(f32x4*)&Lsh[q2 * 64 + mq * 16 + l16 * 4] = lacc[mq];
  }
  __syncthreads();
  if (tw == 0) {
    const int b = bh >> 3, hcol = (bh & 7) * D_;
    float* Ow = Osh + q2 * 4352;
#pragma unroll
    for (int mq = 0; mq < 4; ++mq) {
      const f32x4 lv = *(const f32x4*)&Lsh[q2 * 64 + mq * 16 + l16 * 4];
      f32x4 linv;
#pragma unroll
      for (int r = 0; r < 4; ++r) linv[r] = __builtin_amdgcn_rcpf(lacc[mq][r] + lv[r]);
#pragma unroll
      for (int nd = 0; nd < 4; ++nd) {
        const f32x4 op = *(const f32x4*)&Ow[(nd * 16 + l15) * 68 + mq * 16 + l16 * 4];
#pragma unroll
        for (int r = 0; r < 4; ++r) {
          const int trow = t0q + q2 * 64 + mq * 16 + l16 * 4 + r;
          Out[((size_t)b * T_ + trow) * E_ + hcol + nd * 16 + l15] =
              (__bf16)((oacc[mq][nd][r] + op[r]) * linv[r]);
        }
      }
    }
  }
}

extern "C" void kernel_launch(void* const* d_in, const int* in_sizes, int n_in,
                              void* d_out, int out_size, void* d_ws, size_t ws_size,
                              hipStream_t stream) {
  const float* x    = (const float*)d_in[0];
  const float* Wqkv = (const float*)d_in[1];
  const float* W0   = (const float*)d_in[2];
  float* out = (float*)d_out;

  char* ws = (char*)d_ws;
  __bf16* xb  = (__bf16*)ws;                                    // 8192*512 bf16
  __bf16* wqb = (__bf16*)(ws + 8388608);                        // 1536*512 (permuted)
  __bf16* w0b = (__bf16*)(ws + 8388608 + 1572864);              // 512*512
  __bf16* q   = (__bf16*)(ws + 8388608 + 1572864 + 524288);     // [B,H,D,T]
  __bf16* k   = q + 4194304;                                    // [B,H,T,D]
  __bf16* v   = k + 4194304;                                    // [B,H,D,T]
  __bf16* ao  = xb;  // reuse: xb consumed by QKV GEMM before attn writes ao

  cvt_all<<<2560, 256, 0, stream>>>(x, Wqkv, W0, xb, wqb, w0b);
  gemm_bt<0, 3 * H_ * D_, 128><<<dim3(12, 64), 256, 0, stream>>>(xb, wqb, q, k, v, nullptr);
  attn_kernel<<<dim3(16, 32), 256, 0, stream>>>(q, k, v, ao);
  gemm_bt<1, E_, 64><<<dim3(4, 128), 256, 0, stream>>>(ao, w0b, nullptr, nullptr, nullptr, out);
}

// Round 11
// 150.300 us; speedup vs baseline: 1.4743x; 1.0593x over previous
//
#include <hip/hip_runtime.h>

typedef __bf16 bf16x8 __attribute__((ext_vector_type(8)));
typedef __bf16 bf16x4 __attribute__((ext_vector_type(4)));
typedef float  f32x4  __attribute__((ext_vector_type(4)));

#define B_ 4
#define T_ 2048
#define H_ 8
#define D_ 64
#define E_ 512

// q scale: D^-0.5 * log2(e)  (softmax computed in exp2 domain)
#define QSCALE 0.18033688011112042f

// async global->LDS, 16B per lane. LDS dest is wave-uniform base + lane*16.
__device__ __forceinline__ void async_ld16(const __bf16* g, __bf16* lds) {
  __builtin_amdgcn_global_load_lds((const __attribute__((address_space(1))) void*)g,
                                   (__attribute__((address_space(3))) void*)lds,
                                   16, 0, 0);
}

// converts x, W_qkv (row-permuted to [which][h][d] order), W_0
__global__ void cvt_all(const float* __restrict__ x, const float* __restrict__ wq,
                        const float* __restrict__ w0, __bf16* __restrict__ xb,
                        __bf16* __restrict__ wqb, __bf16* __restrict__ w0b) {
  long i = (long)(blockIdx.x * 256 + threadIdx.x) * 8;
  const float* src; __bf16* dst; long roff, woff;
  if (i < 4194304L)      { src = x;  dst = xb;  roff = i; woff = i; }
  else if (i < 4980736L) {
    src = wq; dst = wqb; roff = i - 4194304L;
    // src row r = h*192 + d*3 + which  ->  dst row = which*512 + h*64 + d
    const int r = (int)(roff >> 9), c = (int)(roff & 511);
    const int h = r / 192, rem = r - h * 192;
    const int d = rem / 3, which = rem - d * 3;
    woff = (long)(which * 512 + h * 64 + d) * 512 + c;
  }
  else                   { src = w0; dst = w0b; roff = i - 4980736L; woff = roff; }
  float4 a = *(const float4*)(src + roff);
  float4 b = *(const float4*)(src + roff + 4);
  bf16x8 o;
  o[0] = (__bf16)a.x; o[1] = (__bf16)a.y; o[2] = (__bf16)a.z; o[3] = (__bf16)a.w;
  o[4] = (__bf16)b.x; o[5] = (__bf16)b.y; o[6] = (__bf16)b.z; o[7] = (__bf16)b.w;
  *(bf16x8*)(dst + woff) = o;
}

// C = A(MxK) * B(NxK)^T, K=512, TMx128 tile, 4 waves, 16x16x32 bf16 MFMA.
// BK=32, 3-slot LDS ring, prefetch depth 2, counted vmcnt (T3/T4).
// MODE 0 (TM=128): qkv epilogue, COALESCED via a two-pass LDS transpose that
// reuses the As object (separate named shared arrays kept exactly as the
// verified R5 kernel; the transpose buffer is a pointer WITHIN As — no
// type-punned union of staging+epilogue storage, which is the one construct
// that differed in the failed R10 attempt). Each m-half (64 rows) is staged
// by the waves owning it (waveM==hh), barrier, then all threads re-read along
// the destination-contiguous axis and emit 16 B coalesced stores (replaces
// 8 B-at-4KB-stride q/v stores and 2 B scalar k stores).
// MODE 1: plain fp32 store, row-major MxN (already 64 B-run coalesced).
template<int MODE, int N, int TM>
__global__ __launch_bounds__(256, TM == 128 ? 3 : 4)
void gemm_bt(const __bf16* __restrict__ A, const __bf16* __restrict__ Bm,
             __bf16* __restrict__ o0, __bf16* __restrict__ o1, __bf16* __restrict__ o2,
             float* __restrict__ of) {
  constexpr int K = 512;
  constexpr int MI = TM / 32;                 // acc tiles in m per wave
  constexpr int AL = TM / 64;                 // A slab-loads per wave per stage
  __shared__ __bf16 As[3][TM * 32];
  __shared__ __bf16 Bs[3][128 * 32];
  const int tid  = threadIdx.x;
  const int wave = tid >> 6, lane = tid & 63;
  const int l15 = lane & 15, l16 = lane >> 4;
  const int m0 = blockIdx.y * TM, n0 = blockIdx.x * 128;
  const int waveM = wave >> 1, waveN = wave & 1;
  // staging lane map: 16-row slab of 32 cols (64 B/row); lane -> (row, chunk)
  const int lr  = lane >> 2;
  const int lc8 = ((lane & 3) ^ ((lane >> 3) & 3)) * 8;

  f32x4 acc[MI][4] = {};

  const __bf16* ag = A  + (size_t)(m0 + wave * (AL * 16) + lr) * K + lc8;
  const __bf16* bg = Bm + (size_t)(n0 + wave * 32 + lr) * K + lc8;

  auto stage = [&](int buf, int k0) {
#pragma unroll
    for (int it = 0; it < AL; ++it)
      async_ld16(ag + (size_t)it * 16 * K + k0, &As[buf][(wave * AL + it) * 512]);
#pragma unroll
    for (int it = 0; it < 2; ++it)
      async_ld16(bg + (size_t)it * 16 * K + k0, &Bs[buf][(wave * 2 + it) * 512]);
  };

  stage(0, 0);
  stage(1, 32);
#pragma unroll
  for (int s = 0; s < 16; ++s) {
    if (s == 15) {
      asm volatile("s_waitcnt vmcnt(0)" ::: "memory");
    } else {
      if constexpr (AL == 2) asm volatile("s_waitcnt vmcnt(4)" ::: "memory");
      else                   asm volatile("s_waitcnt vmcnt(3)" ::: "memory");
    }
    __builtin_amdgcn_s_barrier();
    if (s < 14) stage((s + 2) % 3, (s + 2) * 32);
    const __bf16* Ac = As[s % 3];
    const __bf16* Bc = Bs[s % 3];
    bf16x8 af[MI], bfr[4];
#pragma unroll
    for (int i = 0; i < MI; ++i) {
      const int rA = waveM * (TM / 2) + i * 16 + l15;
      af[i] = *(const bf16x8*)&Ac[rA * 32 + ((l16 ^ ((rA >> 1) & 3)) * 8)];
    }
#pragma unroll
    for (int i = 0; i < 4; ++i) {
      const int rB = waveN * 64 + i * 16 + l15;
      bfr[i] = *(const bf16x8*)&Bc[rB * 32 + ((l16 ^ ((rB >> 1) & 3)) * 8)];
    }
#pragma unroll
    for (int mi = 0; mi < MI; ++mi)
#pragma unroll
      for (int ni = 0; ni < 4; ++ni)
        acc[mi][ni] = __builtin_amdgcn_mfma_f32_16x16x32_bf16(af[mi], bfr[ni], acc[mi][ni], 0, 0, 0);
  }

  if constexpr (MODE == 0) {
    const int which = n0 >> 9;          // block-uniform after W permutation
    const int b = m0 >> 11;
    const int tb = m0 & (T_ - 1);
    const int hbase = (n0 >> 6) & 7;
    __bf16* Eb = &As[0][0];             // 24576 B scratch within the As object
    if (which == 1) {
      // k: per m-half, stage [m'][n] (64x136 bf16 = 17408 B), read n-contiguous
#pragma unroll
      for (int hh = 0; hh < 2; ++hh) {
        __syncthreads();                // K-loop reads / previous pass done
        if (waveM == hh) {
#pragma unroll
          for (int mi = 0; mi < MI; ++mi)
#pragma unroll
            for (int ni = 0; ni < 4; ++ni)
#pragma unroll
              for (int r = 0; r < 4; ++r)
                Eb[(mi * 16 + l16 * 4 + r) * 136 +
                   waveN * 64 + ni * 16 + l15] = (__bf16)acc[mi][ni][r];
        }
        __syncthreads();
#pragma unroll
        for (int it = 0; it < 4; ++it) {
          const int idx = it * 256 + tid;          // 1024 = 64 rows x 16 chunks
          const int mm = idx >> 4, o8 = (idx & 15) * 8;
          const size_t bh = (size_t)(b * H_ + hbase + (o8 >> 6));
          bf16x8 v8 = *(const bf16x8*)&Eb[mm * 136 + o8];
          *(bf16x8*)&o1[(bh * T_ + tb + hh * 64 + mm) * D_ + (o8 & 63)] = v8;
        }
      }
    } else {
      // q,v: per m-half, stage [n][m'] (128x72 bf16 = 18432 B), read t-contiguous
      const float sc = which == 0 ? QSCALE : 1.0f;
      __bf16* dst = which == 0 ? o0 : o2;
#pragma unroll
      for (int hh = 0; hh < 2; ++hh) {
        __syncthreads();
        if (waveM == hh) {
#pragma unroll
          for (int mi = 0; mi < MI; ++mi)
#pragma unroll
            for (int ni = 0; ni < 4; ++ni) {
              bf16x4 pv;
#pragma unroll
              for (int r = 0; r < 4; ++r) pv[r] = (__bf16)(acc[mi][ni][r] * sc);
              *(bf16x4*)&Eb[(waveN * 64 + ni * 16 + l15) * 72 +
                            mi * 16 + l16 * 4] = pv;
            }
        }
        __syncthreads();
#pragma unroll
        for (int it = 0; it < 4; ++it) {
          const int idx = it * 256 + tid;          // 1024 = 128 rows x 8 chunks
          const int n = idx >> 3, o8 = (idx & 7) * 8;
          const size_t bh = (size_t)(b * H_ + hbase + (n >> 6));
          bf16x8 v8 = *(const bf16x8*)&Eb[n * 72 + o8];
          *(bf16x8*)&dst[(bh * D_ + (n & 63)) * T_ + tb + hh * 64 + o8] = v8;
        }
      }
    }
  } else {
#pragma unroll
    for (int mi = 0; mi < MI; ++mi)
#pragma unroll
      for (int ni = 0; ni < 4; ++ni)
#pragma unroll
        for (int r = 0; r < 4; ++r) {
          const int m = m0 + waveM * (TM / 2) + mi * 16 + l16 * 4 + r;
          const int n = n0 + waveN * 64 + ni * 16 + l15;
          of[(size_t)m * N + n] = acc[mi][ni][r];
        }
  }
}

// Flash attention, max-free exp2-domain (R4/R5 structure — best measured,
// 48.1 us; frozen). 4-slot K/V ring, one barrier per 2 tiles. Waves 2x2 over
// (t-half 32, q-half 64). Ps is chunk-XOR swizzled: element P[q][t] lives at
//   q*32 + ((t>>3) ^ ((q>>1)&3))*8 + (t&7)  -> 2-way max on write+read (free).
__global__ __launch_bounds__(256, 2)
void attn_kernel(const __bf16* __restrict__ Q, const __bf16* __restrict__ Kk,
                 const __bf16* __restrict__ Vt, __bf16* __restrict__ Out) {
  __shared__ __align__(16) char smem[81920];
  // K ring[4]:  0, 8192, 16384, 24576        ([64 t][64 d] swizzled)
  // V ring[4]:  32768, 40960, 49152, 57344   ([64 d][64 t] swizzled)
  // Ps: 65536, per-wave [64 q][32 t] chunk-swizzled bf16 (4096 B each, 4 waves).
  float* Osh = (float*)smem;               // overlay: [2 q2][64 d][68] f32
  float* Lsh = (float*)(smem + 34816);     // overlay: [2 q2][64 q'] f32

  const int tid = threadIdx.x, wave = tid >> 6, lane = tid & 63;
  const int l15 = lane & 15, l16 = lane >> 4;
  const int tw = wave >> 1, q2 = wave & 1;
  const int bh  = blockIdx.y;
  const int t0q = blockIdx.x * 128;
  const __bf16* qptr = Q  + (size_t)bh * D_ * T_;   // [D][T], pre-scaled
  const __bf16* kptr = Kk + (size_t)bh * T_ * D_;   // [T][D]
  const __bf16* vptr = Vt + (size_t)bh * D_ * T_;   // [D][T]

  __bf16* Pw = (__bf16*)(smem + 65536) + wave * 2048;   // [64 q][32 t] swizzled
  const int psw = (l15 >> 1) & 3;                       // per-lane chunk XOR key

  // Q fragments (wave's 64 q-cols), from [d][t]: one-time scalar loads.
  bf16x8 qf[4][2];
#pragma unroll
  for (int ni = 0; ni < 4; ++ni)
#pragma unroll
    for (int ks = 0; ks < 2; ++ks)
#pragma unroll
      for (int j = 0; j < 8; ++j)
        qf[ni][ks][j] = qptr[(size_t)(ks * 32 + l16 * 8 + j) * T_ +
                             t0q + q2 * 64 + ni * 16 + l15];

  bf16x8 ones;
#pragma unroll
  for (int j = 0; j < 8; ++j) ones[j] = (__bf16)1.0f;

  f32x4 oacc[4][4] = {};
  f32x4 lacc[4] = {};

  const int srow = lane >> 3;
  const int sch  = (lane & 7) ^ srow;

  auto stage = [&](int buf, int t0k) {
    __bf16* Kd = (__bf16*)(smem + buf * 8192);
    __bf16* Vd = (__bf16*)(smem + 32768 + buf * 8192);
#pragma unroll
    for (int i = 0; i < 2; ++i) {
      const int row = i * 32 + wave * 8;
      async_ld16(kptr + (size_t)(t0k + row + srow) * D_ + sch * 8, Kd + row * 64);
      async_ld16(vptr + (size_t)(row + srow) * T_ + t0k + sch * 8, Vd + row * 64);
    }
  };

  // prologue: first two tiles in flight
  stage(0, 0);
  stage(1, 64);
#pragma unroll 2
  for (int p = 0; p < 16; ++p) {
    __builtin_amdgcn_s_waitcnt(0);
    __syncthreads();
    if (p < 15) {
      stage((2 * p + 2) & 3, (2 * p + 2) * 64);
      stage((2 * p + 3) & 3, (2 * p + 3) * 64);
    }
#pragma unroll
    for (int kk = 0; kk < 2; ++kk) {
      const int kt = 2 * p + kk;
      const __bf16* Ksc = (const __bf16*)(smem + (kt & 3) * 8192);
      const __bf16* Vtc = (const __bf16*)(smem + 32768 + (kt & 3) * 8192);

      // S^T[t'][q'] over wave's 32 t x 64 q (log2 domain via QSCALE)
      f32x4 sacc[2][4] = {};
#pragma unroll
      for (int ks = 0; ks < 2; ++ks) {
        bf16x8 kf[2];
        const int cb = ks * 4 + l16;
#pragma unroll
        for (int mi = 0; mi < 2; ++mi) {
          const int rt = tw * 32 + mi * 16 + l15;
          kf[mi] = *(const bf16x8*)&Ksc[rt * 64 + ((cb ^ (rt & 7)) * 8)];
        }
#pragma unroll
        for (int mi = 0; mi < 2; ++mi)
#pragma unroll
          for (int ni = 0; ni < 4; ++ni)
            sacc[mi][ni] = __builtin_amdgcn_mfma_f32_16x16x32_bf16(kf[mi], qf[ni][ks], sacc[mi][ni], 0, 0, 0);
      }

      // P = exp2(S) -> wave-private Ps, chunk-swizzled.
      // t = mi*16 + l16*4 + r  ->  chunk = mi*2 + (l16>>1), intra = (l16&1)*4 + r
#pragma unroll
      for (int ni = 0; ni < 4; ++ni)
#pragma unroll
        for (int mi = 0; mi < 2; ++mi) {
          bf16x4 pv;
#pragma unroll
          for (int r = 0; r < 4; ++r) pv[r] = (__bf16)__builtin_amdgcn_exp2f(sacc[mi][ni][r]);
          *(bf16x4*)&Pw[(ni * 16 + l15) * 32 +
                        (((mi * 2 + (l16 >> 1)) ^ psw) * 8) + (l16 & 1) * 4] = pv;
        }

      // O += P*V over wave's 32 t ; l += P*1
      // A-frag read: t = l16*8 + j -> chunk = l16, intra = j
      {
        bf16x8 pf[4], vf[4];
#pragma unroll
        for (int mq = 0; mq < 4; ++mq)
          pf[mq] = *(const bf16x8*)&Pw[(mq * 16 + l15) * 32 + ((l16 ^ psw) * 8)];
#pragma unroll
        for (int nd = 0; nd < 4; ++nd) {
          const int rd = nd * 16 + l15;
          const int ct = tw * 4 + l16;
          vf[nd] = *(const bf16x8*)&Vtc[rd * 64 + ((ct ^ (rd & 7)) * 8)];
        }
#pragma unroll
        for (int mq = 0; mq < 4; ++mq) {
#pragma unroll
          for (int nd = 0; nd < 4; ++nd)
            oacc[mq][nd] = __builtin_amdgcn_mfma_f32_16x16x32_bf16(pf[mq], vf[nd], oacc[mq][nd], 0, 0, 0);
          lacc[mq] = __builtin_amdgcn_mfma_f32_16x16x32_bf16(pf[mq], ones, lacc[mq], 0, 0, 0);
        }
      }
    }
  }

  // reduce O,l across t-halves; epilogue O/l -> [B,T,H*D] bf16
  __syncthreads();
  if (tw == 1) {
    float* Ow = Osh + q2 * 4352;            // [64 d][68] f32
#pragma unroll
    for (int mq = 0; mq < 4; ++mq)
#pragma unroll
      for (int nd = 0; nd < 4; ++nd)
        *(f32x4*)&Ow[(nd * 16 + l15) * 68 + mq * 16 + l16 * 4] = oacc[mq][nd];
    if (l15 == 0)
#pragma unroll
      for (int mq = 0; mq < 4; ++mq)
        *(f32x4*)&Lsh[q2 * 64 + mq * 16 + l16 * 4] = lacc[mq];
  }
  __syncthreads();
  if (tw == 0) {
    const int b = bh >> 3, hcol = (bh & 7) * D_;
    float* Ow = Osh + q2 * 4352;
#pragma unroll
    for (int mq = 0; mq < 4; ++mq) {
      const f32x4 lv = *(const f32x4*)&Lsh[q2 * 64 + mq * 16 + l16 * 4];
      f32x4 linv;
#pragma unroll
      for (int r = 0; r < 4; ++r) linv[r] = __builtin_amdgcn_rcpf(lacc[mq][r] + lv[r]);
#pragma unroll
      for (int nd = 0; nd < 4; ++nd) {
        const f32x4 op = *(const f32x4*)&Ow[(nd * 16 + l15) * 68 + mq * 16 + l16 * 4];
#pragma unroll
        for (int r = 0; r < 4; ++r) {
          const int trow = t0q + q2 * 64 + mq * 16 + l16 * 4 + r;
          Out[((size_t)b * T_ + trow) * E_ + hcol + nd * 16 + l15] =
              (__bf16)((oacc[mq][nd][r] + op[r]) * linv[r]);
        }
      }
    }
  }
}

extern "C" void kernel_launch(void* const* d_in, const int* in_sizes, int n_in,
                              void* d_out, int out_size, void* d_ws, size_t ws_size,
                              hipStream_t stream) {
  const float* x    = (const float*)d_in[0];
  const float* Wqkv = (const float*)d_in[1];
  const float* W0   = (const float*)d_in[2];
  float* out = (float*)d_out;

  char* ws = (char*)d_ws;
  __bf16* xb  = (__bf16*)ws;                                    // 8192*512 bf16
  __bf16* wqb = (__bf16*)(ws + 8388608);                        // 1536*512 (permuted)
  __bf16* w0b = (__bf16*)(ws + 8388608 + 1572864);              // 512*512
  __bf16* q   = (__bf16*)(ws + 8388608 + 1572864 + 524288);     // [B,H,D,T]
  __bf16* k   = q + 4194304;                                    // [B,H,T,D]
  __bf16* v   = k + 4194304;                                    // [B,H,D,T]
  __bf16* ao  = xb;  // reuse: xb consumed by QKV GEMM before attn writes ao

  cvt_all<<<2560, 256, 0, stream>>>(x, Wqkv, W0, xb, wqb, w0b);
  gemm_bt<0, 3 * H_ * D_, 128><<<dim3(12, 64), 256, 0, stream>>>(xb, wqb, q, k, v, nullptr);
  attn_kernel<<<dim3(16, 32), 256, 0, stream>>>(q, k, v, ao);
  gemm_bt<1, E_, 64><<<dim3(4, 128), 256, 0, stream>>>(ao, w0b, nullptr, nullptr, nullptr, out);
}